// Round 37
// baseline (117.031 us; speedup 1.0000x reference)
//
#include <hip/hip_runtime.h>

typedef unsigned short u16;
typedef unsigned int u32;
typedef __attribute__((ext_vector_type(8))) short short8;
typedef __attribute__((ext_vector_type(4))) float f32x4;

#define H_ 16
#define L_ 2048
#define D_ 64
#define HID_ 1024

__device__ __forceinline__ u16 f2bf(float f) {
  union { float f; u32 u; } v; v.f = f;
  u32 r = v.u + 0x7FFFu + ((v.u >> 16) & 1u);
  return (u16)(r >> 16);
}

// async global->LDS, 16B per lane
__device__ __forceinline__ void gl16(const u16* g, u16* l) {
  __builtin_amdgcn_global_load_lds(
      (const __attribute__((address_space(1))) void*)g,
      (__attribute__((address_space(3))) void*)l, 16, 0, 0);
}

// ---------------- merged prep kernel: cvt (0..2047) | transpose4 (2048..6143) | rope (6144..6399) ----------------

__global__ __launch_bounds__(256) void prep_k(
    const float* __restrict__ x, u16* __restrict__ xbf,
    const float* __restrict__ Wq, const float* __restrict__ Wk,
    const float* __restrict__ Wv, const float* __restrict__ Wo,
    u16* __restrict__ dWq, u16* __restrict__ dWk,
    u16* __restrict__ dWv, u16* __restrict__ dWo,
    const int* __restrict__ pos, float2* __restrict__ tab)
{
  __shared__ float t[32][33];
  int blk = blockIdx.x;
  if (blk < 2048) {
    // ---- cvt: x f32 -> xbf bf16 (4M elements) ----
    int i = (blk * 256 + threadIdx.x) * 8;
    float4 a = *(const float4*)(x + i);
    float4 b = *(const float4*)(x + i + 4);
    u16 r[8] = { f2bf(a.x), f2bf(a.y), f2bf(a.z), f2bf(a.w),
                 f2bf(b.x), f2bf(b.y), f2bf(b.z), f2bf(b.w) };
    *(uint4*)(xbf + i) = *(const uint4*)r;
  } else if (blk < 6144) {
    // ---- transpose: W [K][N] f32 -> Wt [N][K] bf16 (4 weights) ----
    int bb = blk - 2048;
    int w = bb >> 10;
    const float* in = (w == 0) ? Wq : (w == 1) ? Wk : (w == 2) ? Wv : Wo;
    u16* out = (w == 0) ? dWq : (w == 1) ? dWk : (w == 2) ? dWv : dWo;
    int bx = bb & 31, by = (bb >> 5) & 31;
    int c = threadIdx.x & 31, r0 = threadIdx.x >> 5;
#pragma unroll
    for (int p = 0; p < 4; ++p) {
      int r = r0 + p * 8;
      t[r][c] = in[(size_t)(by * 32 + r) * 1024 + bx * 32 + c];
    }
    __syncthreads();
#pragma unroll
    for (int p = 0; p < 4; ++p) {
      int r = r0 + p * 8;
      out[(size_t)(bx * 32 + r) * 1024 + by * 32 + c] = f2bf(t[c][r]);
    }
  } else {
    // ---- rope table: tab[l][i] = (cos, sin)(pos[l] * base^(-2i/64)) ----
    int gid = (blk - 6144) * 256 + threadIdx.x;
    int l = gid >> 5, i = gid & 31;
    float p = (float)pos[l];
    float inv = expf(-((float)(2 * i) / 64.0f) * logf(10000.0f));
    float th = p * inv;
    tab[gid] = make_float2(cosf(th), sinf(th));
  }
}

// ---------------- fused QKV GEMM v22: 128x192 tiles, 512 blocks (2/CU, one round) ----------------

__global__ __launch_bounds__(256) void qkv_gemm_k(
    const u16* __restrict__ A, const u16* __restrict__ Bt,
    u16* __restrict__ Qo, u16* __restrict__ Ko, u16* __restrict__ Vo,
    const float2* __restrict__ rope)
{
  const int K = 1024;
  __shared__ alignas(16) u16 As[2][8192];    // 128 x 64
  __shared__ alignas(16) u16 Bs[2][12288];   // 192 x 64
  int tid = threadIdx.x;
  int orig = blockIdx.x;               // 0..511
  int xcd = orig & 7, idx = orig >> 3; // 0..63
  int px = xcd & 1, py = xcd >> 1;     // 2 x 4 XCD patch grid
  int tn = px * 8 + (idx & 7);         // 0..15
  int tm = py * 8 + (idx >> 3);        // 0..31
  int m0 = tm * 128, n0 = tn * 192;
  int prow = tid >> 3;
  int pB = (tid & 7) ^ (prow & 7);
  const u16* gA0 = A + (size_t)(m0 + prow) * K + pB * 8;
  const u16* gB0 = Bt + (size_t)(n0 + prow) * K + pB * 8;
  int wid = tid >> 6, lane = tid & 63, ln = lane & 15, kg = lane >> 4;
  int wm = wid * 32;                   // wave rows
  f32x4 acc[2][12] = {};
  int sw0 = (kg ^ (ln & 7)) * 8;
  int sw1 = ((4 + kg) ^ (ln & 7)) * 8;

  auto stage = [&](int kt, int buf) {
#pragma unroll
    for (int s = 0; s < 4; ++s)
      gl16(gA0 + (size_t)s * 32 * K + kt * 64, &As[buf][s * 2048 + tid * 8]);
#pragma unroll
    for (int s = 0; s < 6; ++s)
      gl16(gB0 + (size_t)s * 32 * K + kt * 64, &Bs[buf][s * 2048 + tid * 8]);
  };

  stage(0, 0);
  int cur = 0;
  for (int kt = 0; kt < 16; ++kt) {
    __builtin_amdgcn_s_barrier();
    if (kt + 1 < 16) {
      stage(kt + 1, cur ^ 1);
      asm volatile("s_waitcnt vmcnt(10)" ::: "memory");  // stage(kt) done; kt+1 in flight
    } else {
      asm volatile("s_waitcnt vmcnt(0)" ::: "memory");
    }
    __builtin_amdgcn_sched_barrier(0);
#pragma unroll
    for (int kk = 0; kk < 2; ++kk) {
      int sw = kk ? sw1 : sw0;
      short8 af0 = *(const short8*)&As[cur][(wm + ln) * 64 + sw];
      short8 af1 = *(const short8*)&As[cur][(wm + 16 + ln) * 64 + sw];
#pragma unroll
      for (int nb = 0; nb < 3; ++nb) {
        short8 bq0 = *(const short8*)&Bs[cur][((nb * 64 + 0) + ln) * 64 + sw];
        short8 bq1 = *(const short8*)&Bs[cur][((nb * 64 + 16) + ln) * 64 + sw];
        short8 bq2 = *(const short8*)&Bs[cur][((nb * 64 + 32) + ln) * 64 + sw];
        short8 bq3 = *(const short8*)&Bs[cur][((nb * 64 + 48) + ln) * 64 + sw];
        acc[0][nb * 4 + 0] = __builtin_amdgcn_mfma_f32_16x16x32_bf16(af0, bq0, acc[0][nb * 4 + 0], 0, 0, 0);
        acc[1][nb * 4 + 0] = __builtin_amdgcn_mfma_f32_16x16x32_bf16(af1, bq0, acc[1][nb * 4 + 0], 0, 0, 0);
        acc[0][nb * 4 + 1] = __builtin_amdgcn_mfma_f32_16x16x32_bf16(af0, bq1, acc[0][nb * 4 + 1], 0, 0, 0);
        acc[1][nb * 4 + 1] = __builtin_amdgcn_mfma_f32_16x16x32_bf16(af1, bq1, acc[1][nb * 4 + 1], 0, 0, 0);
        acc[0][nb * 4 + 2] = __builtin_amdgcn_mfma_f32_16x16x32_bf16(af0, bq2, acc[0][nb * 4 + 2], 0, 0, 0);
        acc[1][nb * 4 + 2] = __builtin_amdgcn_mfma_f32_16x16x32_bf16(af1, bq2, acc[1][nb * 4 + 2], 0, 0, 0);
        acc[0][nb * 4 + 3] = __builtin_amdgcn_mfma_f32_16x16x32_bf16(af0, bq3, acc[0][nb * 4 + 3], 0, 0, 0);
        acc[1][nb * 4 + 3] = __builtin_amdgcn_mfma_f32_16x16x32_bf16(af1, bq3, acc[1][nb * 4 + 3], 0, 0, 0);
      }
    }
    cur ^= 1;
  }

  // ---- epilogue: 3 whole heads per tile; per-head section branch ----
#pragma unroll
  for (int hh = 0; hh < 3; ++hh) {
    int gc0 = n0 + hh * 64;            // head-aligned global column base
    int sec = gc0 >> 10;               // 0=Q 1=K 2=V (uniform per head)
    int h = (gc0 & 1023) >> 6;
    if (sec < 2) {
      u16* Out = (sec == 0) ? Qo : Ko;
      float sc = (sec == 0) ? 0.180336880f : 1.0f;   // 0.125 * log2(e)
#pragma unroll
      for (int mi = 0; mi < 2; ++mi)
#pragma unroll
        for (int j = 0; j < 4; ++j) {
          int mm = m0 + wm + mi * 16 + kg * 4 + j;
          int l = mm & (L_ - 1), bb = mm >> 11;
          const float2* tl = rope + l * 32;
#pragma unroll
          for (int g = 0; g < 2; ++g) {
            int dA = g * 16 + ln;      // pairs with dA+32 (acc group g <-> g+2)
            float xa = acc[mi][hh * 4 + g][j], xb = acc[mi][hh * 4 + g + 2][j];
            float2 fA = tl[dA >> 1];
            float2 fB = tl[16 + (dA >> 1)];
            float oA = (fA.x * xa - fA.y * xb) * sc;
            float oB = (fB.x * xb + fB.y * xa) * sc;
            size_t base = ((size_t)(bb * H_ + h) * L_ + l) * D_;
            Out[base + dA] = f2bf(oA);
            Out[base + dA + 32] = f2bf(oB);
          }
        }
    } else {
      // V -> chunk-tiled: Vo[bh][l>>5][d][l&31]
#pragma unroll
      for (int mi = 0; mi < 2; ++mi)
#pragma unroll
        for (int j = 0; j < 4; ++j) {
          int mm = m0 + wm + mi * 16 + kg * 4 + j;
          int l = mm & (L_ - 1), bb = mm >> 11;
          size_t base = (size_t)(bb * H_ + h) * (L_ * D_) + (size_t)(l >> 5) * 2048 + (l & 31);
#pragma unroll
          for (int g = 0; g < 4; ++g) {
            int d = g * 16 + ln;
            Vo[base + (size_t)d * 32] = f2bf(acc[mi][hh * 4 + g][j]);
          }
        }
    }
  }
}

// ---------------- out-projection GEMM v24: BK=64 counted pipeline ----------------

__global__ __launch_bounds__(256) void oproj_k(
    const u16* __restrict__ A, const u16* __restrict__ Bt, float* __restrict__ Out)
{
  const int K = 1024;
  __shared__ alignas(16) u16 As[2][4096];   // 64 x 64
  __shared__ alignas(16) u16 Bs[2][8192];   // 128 x 64
  int tid = threadIdx.x;
  int orig = blockIdx.x;               // 0..511
  int xcd = orig & 7, idx = orig >> 3; // 0..63
  int px = xcd & 1, py = xcd >> 1;
  int tn = px * 4 + (idx & 3);         // 0..7
  int tm = py * 16 + (idx >> 2);       // 0..63
  int m0 = tm * 64, n0 = tn * 128;
  int prow = tid >> 3;
  int pB = (tid & 7) ^ (prow & 7);
  const u16* gA0 = A + (size_t)(m0 + prow) * K + pB * 8;
  const u16* gB0 = Bt + (size_t)(n0 + prow) * K + pB * 8;
  int wid = tid >> 6, lane = tid & 63, ln = lane & 15, kg = lane >> 4;
  int wm = (wid >> 1) * 32, wn = (wid & 1) * 64;
  f32x4 acc[2][4] = {};
  int sw0 = (kg ^ (ln & 7)) * 8;
  int sw1 = ((4 + kg) ^ (ln & 7)) * 8;

  auto stage = [&](int kt, int buf) {
#pragma unroll
    for (int s = 0; s < 2; ++s)
      gl16(gA0 + (size_t)s * 32 * K + kt * 64, &As[buf][s * 2048 + tid * 8]);
#pragma unroll
    for (int s = 0; s < 4; ++s)
      gl16(gB0 + (size_t)s * 32 * K + kt * 64, &Bs[buf][s * 2048 + tid * 8]);
  };

  stage(0, 0);
  int cur = 0;
  for (int kt = 0; kt < 16; ++kt) {
    __builtin_amdgcn_s_barrier();
    if (kt + 1 < 16) {
      stage(kt + 1, cur ^ 1);
      asm volatile("s_waitcnt vmcnt(6)" ::: "memory");   // stage(kt) done; kt+1 in flight
    } else {
      asm volatile("s_waitcnt vmcnt(0)" ::: "memory");
    }
    __builtin_amdgcn_sched_barrier(0);
#pragma unroll
    for (int kk = 0; kk < 2; ++kk) {
      int sw = kk ? sw1 : sw0;
      short8 af[2], bfr[4];
#pragma unroll
      for (int i = 0; i < 2; ++i) af[i] = *(const short8*)&As[cur][(wm + i * 16 + ln) * 64 + sw];
#pragma unroll
      for (int i = 0; i < 4; ++i) bfr[i] = *(const short8*)&Bs[cur][(wn + i * 16 + ln) * 64 + sw];
#pragma unroll
      for (int mi = 0; mi < 2; ++mi)
#pragma unroll
        for (int ni = 0; ni < 4; ++ni)
          acc[mi][ni] = __builtin_amdgcn_mfma_f32_16x16x32_bf16(af[mi], bfr[ni], acc[mi][ni], 0, 0, 0);
    }
    cur ^= 1;
  }
#pragma unroll
  for (int mi = 0; mi < 2; ++mi)
#pragma unroll
    for (int j = 0; j < 4; ++j) {
      int mm = m0 + wm + mi * 16 + kg * 4 + j;
#pragma unroll
      for (int ni = 0; ni < 4; ++ni)
        Out[(size_t)mm * 1024 + n0 + wn + ni * 16 + ln] = acc[mi][ni][j];
    }
}

// ---------------- flash attention v24: equal-pair tiles (2k, 2k+1), 32 q/wave ----------------
// Block = (bh, k): waves 0-1 own tile 2k, waves 2-3 own tile 2k+1; BOTH need exactly
// k+1 chunks -> zero idle waves. Each wave: 32 q rows = two 16-q subtiles sharing
// K/V fragments (LDS reads per FLOP halved vs v20; total block-steps/CU halves).
// Pair map k = (q&1) ? q>>1 : 15-(q>>1) alternates heavy/light so co-resident
// blocks' makespans equalize. Diag mask at c==k: jd = (myTile&1)*4 + w2*2 + s.
__global__ __launch_bounds__(256) void attn_k(
    const u16* __restrict__ Q, const u16* __restrict__ K,
    const u16* __restrict__ V, u16* __restrict__ AO)
{
  __shared__ alignas(16) u16 Ks[2][8192];
  __shared__ alignas(16) u16 Vs[2][8192];
  int tid = threadIdx.x;
  int wid = tid >> 6, lane = tid & 63;
  int ln = lane & 15, kg = lane >> 4;
  int orig = blockIdx.x;               // 0..511
  int swz = (orig & 7) * 64 + (orig >> 3);   // bijective (512 % 8 == 0)
  int bh = swz >> 4;
  int q = swz & 15;
  int k = (q & 1) ? (q >> 1) : (15 - (q >> 1));  // heavy/light alternating
  int NCH = k + 1;                     // chunks needed by BOTH tiles of the pair
  int myTile = 2 * k + (wid >> 1);
  int w2 = wid & 1;
  int q0 = myTile * 64 + w2 * 32;      // wave's 32 q rows: q0..q0+31
  const u16* Qh = Q + (size_t)bh * L_ * D_;
  const u16* Kh = K + (size_t)bh * L_ * D_;
  const u16* Vt = V + (size_t)bh * L_ * D_;   // chunk-tiled [l/32][64][32]

  // staging sources (256 threads; K and V pre-swizzled source, linear LDS dest)
  int srow = tid >> 3, sblk = tid & 7;
  const u16* kb = Kh + (size_t)srow * 64 + ((sblk ^ (srow & 7)) << 3);
  const u16* vb = Vt + (size_t)(tid >> 2) * 32 + (((tid & 3) ^ ((tid >> 3) & 3)) << 3);

  short8 qf00 = *(const short8*)(Qh + (size_t)(q0 + ln) * D_ + kg * 8);
  short8 qf01 = *(const short8*)(Qh + (size_t)(q0 + ln) * D_ + 32 + kg * 8);
  short8 qf10 = *(const short8*)(Qh + (size_t)(q0 + 16 + ln) * D_ + kg * 8);
  short8 qf11 = *(const short8*)(Qh + (size_t)(q0 + 16 + ln) * D_ + 32 + kg * 8);

  f32x4 o0[4] = {}, o1[4] = {};
  float ls0 = 0.f, ls1 = 0.f;
  int srcA = ln + (((2 * kg) & 3) << 4);
  int srcB = ln + (((2 * kg + 1) & 3) << 4);
  bool thi = (kg >= 2);
  int sw0 = (kg ^ (ln & 7)) * 8;
  int sw1 = ((4 + kg) ^ (ln & 7)) * 8;
  int vsw = (kg ^ ((ln >> 1) & 3)) * 8;   // V read block swizzle
  int jdbase = (myTile & 1) * 4 + w2 * 2; // subtile0 diag sub-tile; subtile1 = +1

  auto stage = [&](int chunk, int buf) {
    const u16* kc = kb + (size_t)chunk * 8192;
    const u16* vc = vb + (size_t)chunk * 8192;
#pragma unroll
    for (int s2 = 0; s2 < 4; ++s2) {
      gl16(kc + s2 * 2048, &Ks[buf][s2 * 2048 + tid * 8]);
      gl16(vc + s2 * 2048, &Vs[buf][s2 * 2048 + tid * 8]);
    }
  };

  stage(0, 0);
  int cur = 0;

  for (int c = 0; c < NCH; ++c) {
    __builtin_amdgcn_s_barrier();
    if (c + 1 < NCH) {
      stage(c + 1, cur ^ 1);
      asm volatile("s_waitcnt vmcnt(8)" ::: "memory");   // stage(c) done; c+1 in flight
    } else {
      asm volatile("s_waitcnt vmcnt(0)" ::: "memory");
    }
    __builtin_amdgcn_sched_barrier(0);

    int jd0 = (c == NCH - 1) ? jdbase : 8;
    // ---- QK^T for both subtiles (shared K fragments) ----
    f32x4 s0[8], s1[8];
    __builtin_amdgcn_s_setprio(1);
#pragma unroll
    for (int j = 0; j < 8; ++j) {
      short8 ka = *(const short8*)&Ks[cur][(j * 16 + ln) * 64 + sw0];
      short8 kc = *(const short8*)&Ks[cur][(j * 16 + ln) * 64 + sw1];
      f32x4 t = {};
      t = __builtin_amdgcn_mfma_f32_16x16x32_bf16(ka, qf00, t, 0, 0, 0);
      t = __builtin_amdgcn_mfma_f32_16x16x32_bf16(kc, qf01, t, 0, 0, 0);
      s0[j] = t;
      f32x4 u = {};
      u = __builtin_amdgcn_mfma_f32_16x16x32_bf16(ka, qf10, u, 0, 0, 0);
      u = __builtin_amdgcn_mfma_f32_16x16x32_bf16(kc, qf11, u, 0, 0, 0);
      s1[j] = u;
    }
    __builtin_amdgcn_s_setprio(0);
    if (jd0 < 8) {                     // diagonal chunk: mask both subtiles
      int jd1 = jd0 + 1;
#pragma unroll
      for (int j = 0; j < 8; ++j)
#pragma unroll
        for (int r = 0; r < 4; ++r) {
          bool k0 = (j > jd0) | ((j == jd0) & ((kg * 4 + r) > ln));
          if (k0) s0[j][r] = -1e30f;
          bool k1 = (j > jd1) | ((j == jd1) & ((kg * 4 + r) > ln));
          if (k1) s1[j][r] = -1e30f;
        }
    }
    // ---- fixed-max exp2 softmax, both subtiles ----
    float ps0 = 0.f, ps1 = 0.f;
    u32 wA0[8], wB0[8], wA1[8], wB1[8];
#pragma unroll
    for (int j = 0; j < 8; ++j) {
      float a0, a1, a2, a3, b0, b1, b2, b3;
      asm("v_exp_f32 %0, %1" : "=v"(a0) : "v"(s0[j][0]));
      asm("v_exp_f32 %0, %1" : "=v"(a1) : "v"(s0[j][1]));
      asm("v_exp_f32 %0, %1" : "=v"(a2) : "v"(s0[j][2]));
      asm("v_exp_f32 %0, %1" : "=v"(a3) : "v"(s0[j][3]));
      asm("v_exp_f32 %0, %1" : "=v"(b0) : "v"(s1[j][0]));
      asm("v_exp_f32 %0, %1" : "=v"(b1) : "v"(s1[j][1]));
      asm("v_exp_f32 %0, %1" : "=v"(b2) : "v"(s1[j][2]));
      asm("v_exp_f32 %0, %1" : "=v"(b3) : "v"(s1[j][3]));
      ps0 += (a0 + a1) + (a2 + a3);
      ps1 += (b0 + b1) + (b2 + b3);
      asm("v_cvt_pk_bf16_f32 %0, %1, %2" : "=v"(wA0[j]) : "v"(a0), "v"(a1));
      asm("v_cvt_pk_bf16_f32 %0, %1, %2" : "=v"(wB0[j]) : "v"(a2), "v"(a3));
      asm("v_cvt_pk_bf16_f32 %0, %1, %2" : "=v"(wA1[j]) : "v"(b0), "v"(b1));
      asm("v_cvt_pk_bf16_f32 %0, %1, %2" : "=v"(wB1[j]) : "v"(b2), "v"(b3));
    }
    ls0 += ps0;
    ls1 += ps1;
    // ---- P^T gather + PV (shared V fragments) ----
#pragma unroll
    for (int g = 0; g < 4; ++g) {
      int j0 = 2 * g, j1 = j0 + 1;
      u32 x0 = __shfl((int)wA0[j0], srcA), x1 = __shfl((int)wA0[j1], srcA);
      u32 x2 = __shfl((int)wB0[j0], srcA), x3 = __shfl((int)wB0[j1], srcA);
      u32 x4 = __shfl((int)wA0[j0], srcB), x5 = __shfl((int)wA0[j1], srcB);
      u32 x6 = __shfl((int)wB0[j0], srcB), x7 = __shfl((int)wB0[j1], srcB);
      union { u32 u[4]; short8 s8; } pu0;
      pu0.u[0] = thi ? x1 : x0;
      pu0.u[1] = thi ? x3 : x2;
      pu0.u[2] = thi ? x5 : x4;
      pu0.u[3] = thi ? x7 : x6;
      u32 y0 = __shfl((int)wA1[j0], srcA), y1 = __shfl((int)wA1[j1], srcA);
      u32 y2 = __shfl((int)wB1[j0], srcA), y3 = __shfl((int)wB1[j1], srcA);
      u32 y4 = __shfl((int)wA1[j0], srcB), y5 = __shfl((int)wA1[j1], srcB);
      u32 y6 = __shfl((int)wB1[j0], srcB), y7 = __shfl((int)wB1[j1], srcB);
      union { u32 u[4]; short8 s8; } pu1;
      pu1.u[0] = thi ? y1 : y0;
      pu1.u[1] = thi ? y3 : y2;
      pu1.u[2] = thi ? y5 : y4;
      pu1.u[3] = thi ? y7 : y6;
      short8 vf0 = *(const short8*)&Vs[cur][g * 2048 + ln * 32 + vsw];
      short8 vf1 = *(const short8*)&Vs[cur][g * 2048 + (16 + ln) * 32 + vsw];
      short8 vf2 = *(const short8*)&Vs[cur][g * 2048 + (32 + ln) * 32 + vsw];
      short8 vf3 = *(const short8*)&Vs[cur][g * 2048 + (48 + ln) * 32 + vsw];
      __builtin_amdgcn_s_setprio(1);
      o0[0] = __builtin_amdgcn_mfma_f32_16x16x32_bf16(vf0, pu0.s8, o0[0], 0, 0, 0);
      o0[1] = __builtin_amdgcn_mfma_f32_16x16x32_bf16(vf1, pu0.s8, o0[1], 0, 0, 0);
      o0[2] = __builtin_amdgcn_mfma_f32_16x16x32_bf16(vf2, pu0.s8, o0[2], 0, 0, 0);
      o0[3] = __builtin_amdgcn_mfma_f32_16x16x32_bf16(vf3, pu0.s8, o0[3], 0, 0, 0);
      o1[0] = __builtin_amdgcn_mfma_f32_16x16x32_bf16(vf0, pu1.s8, o1[0], 0, 0, 0);
      o1[1] = __builtin_amdgcn_mfma_f32_16x16x32_bf16(vf1, pu1.s8, o1[1], 0, 0, 0);
      o1[2] = __builtin_amdgcn_mfma_f32_16x16x32_bf16(vf2, pu1.s8, o1[2], 0, 0, 0);
      o1[3] = __builtin_amdgcn_mfma_f32_16x16x32_bf16(vf3, pu1.s8, o1[3], 0, 0, 0);
      __builtin_amdgcn_s_setprio(0);
    }
    cur ^= 1;
  }

  // ---- final l reduction + store, both subtiles ----
  int b = bh >> 4, h = bh & 15;
  ls0 += __shfl_xor(ls0, 16);
  ls0 += __shfl_xor(ls0, 32);
  ls1 += __shfl_xor(ls1, 16);
  ls1 += __shfl_xor(ls1, 32);
  float inv0 = 1.0f / ls0, inv1 = 1.0f / ls1;
  u16* row0 = AO + ((size_t)(b * L_ + q0 + ln) * H_ + h) * D_;
  u16* row1 = AO + ((size_t)(b * L_ + q0 + 16 + ln) * H_ + h) * D_;
#pragma unroll
  for (int dt = 0; dt < 4; ++dt) {
    union { u16 pk[4]; uint2 v; } u0, u1;
#pragma unroll
    for (int r = 0; r < 4; ++r) {
      u0.pk[r] = f2bf(o0[dt][r] * inv0);
      u1.pk[r] = f2bf(o1[dt][r] * inv1);
    }
    *(uint2*)(row0 + dt * 16 + kg * 4) = u0.v;
    *(uint2*)(row1 + dt * 16 + kg * 4) = u1.v;
  }
}

// ---------------- launch ----------------

extern "C" void kernel_launch(void* const* d_in, const int* in_sizes, int n_in,
                              void* d_out, int out_size, void* d_ws, size_t ws_size,
                              hipStream_t stream) {
  (void)in_sizes; (void)n_in; (void)out_size; (void)ws_size;
  const float* x   = (const float*)d_in[0];
  const int*   pos = (const int*)d_in[1];
  // d_in[2] = additive causal mask (we apply causal masking directly)
  const float* Wq  = (const float*)d_in[3];
  const float* Wk  = (const float*)d_in[4];
  const float* Wv  = (const float*)d_in[5];
  const float* Wo  = (const float*)d_in[6];

  char* ws = (char*)d_ws;
  u16* xbf = (u16*)ws;                        // 8 MB
  u16* Wt3 = (u16*)(ws + (size_t)( 8 << 20)); // 6 MB ([Wq|Wk|Wv]^T stacked)
  u16* Wto = (u16*)(ws + (size_t)(14 << 20)); // 2 MB
  u16* Qb  = (u16*)(ws + (size_t)(16 << 20)); // 8 MB each
  u16* Kb  = (u16*)(ws + (size_t)(24 << 20));
  u16* Vt  = (u16*)(ws + (size_t)(32 << 20)); // chunk-tiled
  u16* AO  = (u16*)(ws + (size_t)(40 << 20));
  float2* tab = (float2*)(ws + (size_t)(48 << 20)); // 512 KB

  prep_k<<<6400, 256, 0, stream>>>(
      x, xbf, Wq, Wk, Wv, Wo,
      Wt3, Wt3 + (size_t)1048576, Wt3 + (size_t)2097152, Wto, pos, tab);
  qkv_gemm_k<<<512, 256, 0, stream>>>(xbf, Wt3, Qb, Kb, Vt, tab);
  attn_k<<<512, 256, 0, stream>>>(Qb, Kb, Vt, AO);
  oproj_k<<<512, 256, 0, stream>>>(AO, Wto, (float*)d_out);
}

// Round 38
// 94.708 us; speedup vs baseline: 1.2357x; 1.2357x over previous
//
#include <hip/hip_runtime.h>

typedef unsigned short u16;
typedef unsigned int u32;
typedef __attribute__((ext_vector_type(8))) short short8;
typedef __attribute__((ext_vector_type(4))) float f32x4;

#define H_ 16
#define L_ 2048
#define D_ 64
#define HID_ 1024

__device__ __forceinline__ u16 f2bf(float f) {
  union { float f; u32 u; } v; v.f = f;
  u32 r = v.u + 0x7FFFu + ((v.u >> 16) & 1u);
  return (u16)(r >> 16);
}

// async global->LDS, 16B per lane
__device__ __forceinline__ void gl16(const u16* g, u16* l) {
  __builtin_amdgcn_global_load_lds(
      (const __attribute__((address_space(1))) void*)g,
      (__attribute__((address_space(3))) void*)l, 16, 0, 0);
}

// ---------------- merged prep kernel: cvt (0..2047) | transpose4 (2048..6143) | rope (6144..6399) ----------------

__global__ __launch_bounds__(256) void prep_k(
    const float* __restrict__ x, u16* __restrict__ xbf,
    const float* __restrict__ Wq, const float* __restrict__ Wk,
    const float* __restrict__ Wv, const float* __restrict__ Wo,
    u16* __restrict__ dWq, u16* __restrict__ dWk,
    u16* __restrict__ dWv, u16* __restrict__ dWo,
    const int* __restrict__ pos, float2* __restrict__ tab)
{
  __shared__ float t[32][33];
  int blk = blockIdx.x;
  if (blk < 2048) {
    // ---- cvt: x f32 -> xbf bf16 (4M elements) ----
    int i = (blk * 256 + threadIdx.x) * 8;
    float4 a = *(const float4*)(x + i);
    float4 b = *(const float4*)(x + i + 4);
    u16 r[8] = { f2bf(a.x), f2bf(a.y), f2bf(a.z), f2bf(a.w),
                 f2bf(b.x), f2bf(b.y), f2bf(b.z), f2bf(b.w) };
    *(uint4*)(xbf + i) = *(const uint4*)r;
  } else if (blk < 6144) {
    // ---- transpose: W [K][N] f32 -> Wt [N][K] bf16 (4 weights) ----
    int bb = blk - 2048;
    int w = bb >> 10;
    const float* in = (w == 0) ? Wq : (w == 1) ? Wk : (w == 2) ? Wv : Wo;
    u16* out = (w == 0) ? dWq : (w == 1) ? dWk : (w == 2) ? dWv : dWo;
    int bx = bb & 31, by = (bb >> 5) & 31;
    int c = threadIdx.x & 31, r0 = threadIdx.x >> 5;
#pragma unroll
    for (int p = 0; p < 4; ++p) {
      int r = r0 + p * 8;
      t[r][c] = in[(size_t)(by * 32 + r) * 1024 + bx * 32 + c];
    }
    __syncthreads();
#pragma unroll
    for (int p = 0; p < 4; ++p) {
      int r = r0 + p * 8;
      out[(size_t)(bx * 32 + r) * 1024 + by * 32 + c] = f2bf(t[c][r]);
    }
  } else {
    // ---- rope table: tab[l][i] = (cos, sin)(pos[l] * base^(-2i/64)) ----
    int gid = (blk - 6144) * 256 + threadIdx.x;
    int l = gid >> 5, i = gid & 31;
    float p = (float)pos[l];
    float inv = expf(-((float)(2 * i) / 64.0f) * logf(10000.0f));
    float th = p * inv;
    tab[gid] = make_float2(cosf(th), sinf(th));
  }
}

// ---------------- fused QKV GEMM v22: 128x192 tiles, 512 blocks (2/CU, one round) ----------------
// V epilogue v25: kv rows stored PERMUTED within each 32-chunk (slotpos) so attn's
// PV B-operand needs no cross-lane shuffles (sum over kv is permutation-invariant).

__global__ __launch_bounds__(256) void qkv_gemm_k(
    const u16* __restrict__ A, const u16* __restrict__ Bt,
    u16* __restrict__ Qo, u16* __restrict__ Ko, u16* __restrict__ Vo,
    const float2* __restrict__ rope)
{
  const int K = 1024;
  __shared__ alignas(16) u16 As[2][8192];    // 128 x 64
  __shared__ alignas(16) u16 Bs[2][12288];   // 192 x 64
  int tid = threadIdx.x;
  int orig = blockIdx.x;               // 0..511
  int xcd = orig & 7, idx = orig >> 3; // 0..63
  int px = xcd & 1, py = xcd >> 1;     // 2 x 4 XCD patch grid
  int tn = px * 8 + (idx & 7);         // 0..15
  int tm = py * 8 + (idx >> 3);        // 0..31
  int m0 = tm * 128, n0 = tn * 192;
  // staging source (pre-swizzled): thread t, pass s -> row s*32+(t>>3), block B
  int prow = tid >> 3;
  int pB = (tid & 7) ^ (prow & 7);
  const u16* gA0 = A + (size_t)(m0 + prow) * K + pB * 8;
  const u16* gB0 = Bt + (size_t)(n0 + prow) * K + pB * 8;
  int wid = tid >> 6, lane = tid & 63, ln = lane & 15, kg = lane >> 4;
  int wm = wid * 32;                   // wave rows
  f32x4 acc[2][12] = {};
  // swizzled read offsets: row r, k-half kk, block (kk*4+kg)^(r&7)
  int sw0 = (kg ^ (ln & 7)) * 8;
  int sw1 = ((4 + kg) ^ (ln & 7)) * 8;

  auto stage = [&](int kt, int buf) {
#pragma unroll
    for (int s = 0; s < 4; ++s)
      gl16(gA0 + (size_t)s * 32 * K + kt * 64, &As[buf][s * 2048 + tid * 8]);
#pragma unroll
    for (int s = 0; s < 6; ++s)
      gl16(gB0 + (size_t)s * 32 * K + kt * 64, &Bs[buf][s * 2048 + tid * 8]);
  };

  stage(0, 0);
  int cur = 0;
  for (int kt = 0; kt < 16; ++kt) {
    __builtin_amdgcn_s_barrier();
    if (kt + 1 < 16) {
      stage(kt + 1, cur ^ 1);
      asm volatile("s_waitcnt vmcnt(10)" ::: "memory");  // stage(kt) done; kt+1 in flight
    } else {
      asm volatile("s_waitcnt vmcnt(0)" ::: "memory");
    }
    __builtin_amdgcn_sched_barrier(0);
#pragma unroll
    for (int kk = 0; kk < 2; ++kk) {
      int sw = kk ? sw1 : sw0;
      short8 af0 = *(const short8*)&As[cur][(wm + ln) * 64 + sw];
      short8 af1 = *(const short8*)&As[cur][(wm + 16 + ln) * 64 + sw];
#pragma unroll
      for (int nb = 0; nb < 3; ++nb) {
        short8 bq0 = *(const short8*)&Bs[cur][((nb * 64 + 0) + ln) * 64 + sw];
        short8 bq1 = *(const short8*)&Bs[cur][((nb * 64 + 16) + ln) * 64 + sw];
        short8 bq2 = *(const short8*)&Bs[cur][((nb * 64 + 32) + ln) * 64 + sw];
        short8 bq3 = *(const short8*)&Bs[cur][((nb * 64 + 48) + ln) * 64 + sw];
        acc[0][nb * 4 + 0] = __builtin_amdgcn_mfma_f32_16x16x32_bf16(af0, bq0, acc[0][nb * 4 + 0], 0, 0, 0);
        acc[1][nb * 4 + 0] = __builtin_amdgcn_mfma_f32_16x16x32_bf16(af1, bq0, acc[1][nb * 4 + 0], 0, 0, 0);
        acc[0][nb * 4 + 1] = __builtin_amdgcn_mfma_f32_16x16x32_bf16(af0, bq1, acc[0][nb * 4 + 1], 0, 0, 0);
        acc[1][nb * 4 + 1] = __builtin_amdgcn_mfma_f32_16x16x32_bf16(af1, bq1, acc[1][nb * 4 + 1], 0, 0, 0);
        acc[0][nb * 4 + 2] = __builtin_amdgcn_mfma_f32_16x16x32_bf16(af0, bq2, acc[0][nb * 4 + 2], 0, 0, 0);
        acc[1][nb * 4 + 2] = __builtin_amdgcn_mfma_f32_16x16x32_bf16(af1, bq2, acc[1][nb * 4 + 2], 0, 0, 0);
        acc[0][nb * 4 + 3] = __builtin_amdgcn_mfma_f32_16x16x32_bf16(af0, bq3, acc[0][nb * 4 + 3], 0, 0, 0);
        acc[1][nb * 4 + 3] = __builtin_amdgcn_mfma_f32_16x16x32_bf16(af1, bq3, acc[1][nb * 4 + 3], 0, 0, 0);
      }
    }
    cur ^= 1;
  }

  // ---- epilogue: 3 whole heads per tile; per-head section branch ----
#pragma unroll
  for (int hh = 0; hh < 3; ++hh) {
    int gc0 = n0 + hh * 64;            // head-aligned global column base
    int sec = gc0 >> 10;               // 0=Q 1=K 2=V (uniform per head)
    int h = (gc0 & 1023) >> 6;
    if (sec < 2) {
      u16* Out = (sec == 0) ? Qo : Ko;
      float sc = (sec == 0) ? 0.180336880f : 1.0f;   // 0.125 * log2(e)
#pragma unroll
      for (int mi = 0; mi < 2; ++mi)
#pragma unroll
        for (int j = 0; j < 4; ++j) {
          int mm = m0 + wm + mi * 16 + kg * 4 + j;
          int l = mm & (L_ - 1), bb = mm >> 11;
          const float2* tl = rope + l * 32;
#pragma unroll
          for (int g = 0; g < 2; ++g) {
            int dA = g * 16 + ln;      // pairs with dA+32 (acc group g <-> g+2)
            float xa = acc[mi][hh * 4 + g][j], xb = acc[mi][hh * 4 + g + 2][j];
            float2 fA = tl[dA >> 1];
            float2 fB = tl[16 + (dA >> 1)];
            float oA = (fA.x * xa - fA.y * xb) * sc;
            float oB = (fB.x * xb + fB.y * xa) * sc;
            size_t base = ((size_t)(bb * H_ + h) * L_ + l) * D_;
            Out[base + dA] = f2bf(oA);
            Out[base + dA + 32] = f2bf(oB);
          }
        }
    } else {
      // V -> chunk-tiled + kv-permuted: Vo[bh][l>>5][d][slotpos(l&31)]
      // slotpos(m) = ((m>>2)&3)*8 + ((m>>4)&1)*4 + (m&3): PV B-operand slot
      // 8kg+4h+2p+e holds kv 16h+4kg+2p+e -> attn needs zero shuffles.
#pragma unroll
      for (int mi = 0; mi < 2; ++mi)
#pragma unroll
        for (int j = 0; j < 4; ++j) {
          int mm = m0 + wm + mi * 16 + kg * 4 + j;
          int l = mm & (L_ - 1), bb = mm >> 11;
          int m = l & 31;
          int sp = ((m >> 2) & 3) * 8 + ((m >> 4) & 1) * 4 + (m & 3);
          size_t base = (size_t)(bb * H_ + h) * (L_ * D_) + (size_t)(l >> 5) * 2048 + sp;
#pragma unroll
          for (int g = 0; g < 4; ++g) {
            int d = g * 16 + ln;
            Vo[base + (size_t)d * 32] = f2bf(acc[mi][hh * 4 + g][j]);
          }
        }
    }
  }
}

// ---------------- out-projection GEMM v24: BK=64 counted pipeline ----------------

__global__ __launch_bounds__(256) void oproj_k(
    const u16* __restrict__ A, const u16* __restrict__ Bt, float* __restrict__ Out)
{
  const int K = 1024;
  __shared__ alignas(16) u16 As[2][4096];   // 64 x 64
  __shared__ alignas(16) u16 Bs[2][8192];   // 128 x 64
  int tid = threadIdx.x;
  int orig = blockIdx.x;               // 0..511
  int xcd = orig & 7, idx = orig >> 3; // 0..63
  int px = xcd & 1, py = xcd >> 1;
  int tn = px * 4 + (idx & 3);         // 0..7
  int tm = py * 16 + (idx >> 2);       // 0..63
  int m0 = tm * 64, n0 = tn * 128;
  int prow = tid >> 3;
  int pB = (tid & 7) ^ (prow & 7);
  const u16* gA0 = A + (size_t)(m0 + prow) * K + pB * 8;
  const u16* gB0 = Bt + (size_t)(n0 + prow) * K + pB * 8;
  int wid = tid >> 6, lane = tid & 63, ln = lane & 15, kg = lane >> 4;
  int wm = (wid >> 1) * 32, wn = (wid & 1) * 64;
  f32x4 acc[2][4] = {};
  int sw0 = (kg ^ (ln & 7)) * 8;
  int sw1 = ((4 + kg) ^ (ln & 7)) * 8;

  auto stage = [&](int kt, int buf) {
#pragma unroll
    for (int s = 0; s < 2; ++s)
      gl16(gA0 + (size_t)s * 32 * K + kt * 64, &As[buf][s * 2048 + tid * 8]);
#pragma unroll
    for (int s = 0; s < 4; ++s)
      gl16(gB0 + (size_t)s * 32 * K + kt * 64, &Bs[buf][s * 2048 + tid * 8]);
  };

  stage(0, 0);
  int cur = 0;
  for (int kt = 0; kt < 16; ++kt) {
    __builtin_amdgcn_s_barrier();
    if (kt + 1 < 16) {
      stage(kt + 1, cur ^ 1);
      asm volatile("s_waitcnt vmcnt(6)" ::: "memory");   // stage(kt) done; kt+1 in flight
    } else {
      asm volatile("s_waitcnt vmcnt(0)" ::: "memory");
    }
    __builtin_amdgcn_sched_barrier(0);
#pragma unroll
    for (int kk = 0; kk < 2; ++kk) {
      int sw = kk ? sw1 : sw0;
      short8 af[2], bfr[4];
#pragma unroll
      for (int i = 0; i < 2; ++i) af[i] = *(const short8*)&As[cur][(wm + i * 16 + ln) * 64 + sw];
#pragma unroll
      for (int i = 0; i < 4; ++i) bfr[i] = *(const short8*)&Bs[cur][(wn + i * 16 + ln) * 64 + sw];
#pragma unroll
      for (int mi = 0; mi < 2; ++mi)
#pragma unroll
        for (int ni = 0; ni < 4; ++ni)
          acc[mi][ni] = __builtin_amdgcn_mfma_f32_16x16x32_bf16(af[mi], bfr[ni], acc[mi][ni], 0, 0, 0);
    }
    cur ^= 1;
  }
#pragma unroll
  for (int mi = 0; mi < 2; ++mi)
#pragma unroll
    for (int j = 0; j < 4; ++j) {
      int mm = m0 + wm + mi * 16 + kg * 4 + j;
#pragma unroll
      for (int ni = 0; ni < 4; ++ni)
        Out[(size_t)mm * 1024 + n0 + wn + ni * 16 + ln] = acc[mi][ni][j];
    }
}

// ---------------- flash attention v25: v20 structure + zero-shuffle PV ----------------
// V is stored kv-permuted (qkv epilogue slotpos) so the PV B-operand is exactly
// the lane-local (wA,wB) pairs: pu = {wA[2g], wB[2g], wA[2g+1], wB[2g+1]}.
// All 32 bpermutes per step deleted -> LDS pipe load ~halved.
__global__ __launch_bounds__(256) void attn_k(
    const u16* __restrict__ Q, const u16* __restrict__ K,
    const u16* __restrict__ V, u16* __restrict__ AO)
{
  __shared__ alignas(16) u16 Ks[2][8192];
  __shared__ alignas(16) u16 Vs[2][8192];
  int tid = threadIdx.x;
  int wid = tid >> 6, lane = tid & 63;
  int ln = lane & 15, kg = lane >> 4;
  int orig = blockIdx.x;               // 0..511
  int swz = (orig & 7) * 64 + (orig >> 3);   // bijective (512 % 8 == 0)
  int bh = swz >> 4;
  int i = swz & 15;
  int tA = i, tB = 31 - i;
  int nA = (tA >> 1) + 1;              // 128-kv chunks for tile A
  int nB = (tB >> 1) + 1;
  const int NCH = 17;                  // nA + nB = 17 for every i
  int q0A = tA * 64 + wid * 16;
  int q0B = tB * 64 + wid * 16;
  const u16* Qh = Q + (size_t)bh * L_ * D_;
  const u16* Kh = K + (size_t)bh * L_ * D_;
  const u16* Vt = V + (size_t)bh * L_ * D_;   // chunk-tiled [l/32][64][32], kv-permuted

  // staging sources (256 threads; K and V pre-swizzled source, linear LDS dest)
  int srow = tid >> 3, sblk = tid & 7;
  const u16* kb = Kh + (size_t)srow * 64 + ((sblk ^ (srow & 7)) << 3);
  const u16* vb = Vt + (size_t)(tid >> 2) * 32 + (((tid & 3) ^ ((tid >> 3) & 3)) << 3);

  short8 qfA0 = *(const short8*)(Qh + (size_t)(q0A + ln) * D_ + kg * 8);
  short8 qfA1 = *(const short8*)(Qh + (size_t)(q0A + ln) * D_ + 32 + kg * 8);
  short8 qfB0 = *(const short8*)(Qh + (size_t)(q0B + ln) * D_ + kg * 8);
  short8 qfB1 = *(const short8*)(Qh + (size_t)(q0B + ln) * D_ + 32 + kg * 8);

  f32x4 oA[4] = {}, oB[4] = {};
  float lsA = 0.f, lsB = 0.f;
  int sw0 = (kg ^ (ln & 7)) * 8;
  int sw1 = ((4 + kg) ^ (ln & 7)) * 8;
  int vsw = (kg ^ ((ln >> 1) & 3)) * 8;   // V read block swizzle
  int jdA = (tA & 1) * 4 + wid;        // diag sub-tile in tile A's last chunk
  int jdB = (tB & 1) * 4 + wid;

  auto stage = [&](int chunk, int buf) {
    const u16* kc = kb + (size_t)chunk * 8192;
    const u16* vc = vb + (size_t)chunk * 8192;
#pragma unroll
    for (int s2 = 0; s2 < 4; ++s2) {
      gl16(kc + s2 * 2048, &Ks[buf][s2 * 2048 + tid * 8]);
      gl16(vc + s2 * 2048, &Vs[buf][s2 * 2048 + tid * 8]);
    }
  };
  auto seq = [&](int c) { return (c < nA) ? c : c - nA; };

  // one 128-kv chunk step for one 16-q tile. jd: 0..7 = diagonal sub-tile
  // (mask j>jd fully, j==jd elementwise); 8 = no masking.
  auto step = [&](int cur, int jd, short8 qf0, short8 qf1,
                  float& lsum, f32x4 (&o)[4]) {
    f32x4 s[8];
    __builtin_amdgcn_s_setprio(1);
#pragma unroll
    for (int j = 0; j < 8; ++j) {
      short8 ka = *(const short8*)&Ks[cur][(j * 16 + ln) * 64 + sw0];
      short8 kc = *(const short8*)&Ks[cur][(j * 16 + ln) * 64 + sw1];
      f32x4 t = {};
      t = __builtin_amdgcn_mfma_f32_16x16x32_bf16(ka, qf0, t, 0, 0, 0);
      t = __builtin_amdgcn_mfma_f32_16x16x32_bf16(kc, qf1, t, 0, 0, 0);
      s[j] = t;
    }
    __builtin_amdgcn_s_setprio(0);
    if (jd < 8) {                      // wave-uniform branch
#pragma unroll
      for (int j = 0; j < 8; ++j)
#pragma unroll
        for (int r = 0; r < 4; ++r) {
          bool kill = (j > jd) | ((j == jd) & ((kg * 4 + r) > ln));
          if (kill) s[j][r] = -1e30f;
        }
    }
    float ps = 0.f;
    u32 wA[8], wB[8];
#pragma unroll
    for (int j = 0; j < 8; ++j) {
      float p0, p1, p2, p3;
      asm("v_exp_f32 %0, %1" : "=v"(p0) : "v"(s[j][0]));
      asm("v_exp_f32 %0, %1" : "=v"(p1) : "v"(s[j][1]));
      asm("v_exp_f32 %0, %1" : "=v"(p2) : "v"(s[j][2]));
      asm("v_exp_f32 %0, %1" : "=v"(p3) : "v"(s[j][3]));
      ps += (p0 + p1) + (p2 + p3);
      asm("v_cvt_pk_bf16_f32 %0, %1, %2" : "=v"(wA[j]) : "v"(p0), "v"(p1));
      asm("v_cvt_pk_bf16_f32 %0, %1, %2" : "=v"(wB[j]) : "v"(p2), "v"(p3));
    }
    lsum += ps;
#pragma unroll
    for (int g = 0; g < 4; ++g) {
      // zero-shuffle PV: V slot order matches native P distribution
      union { u32 u[4]; short8 s8; } pu;
      pu.u[0] = wA[2 * g];
      pu.u[1] = wB[2 * g];
      pu.u[2] = wA[2 * g + 1];
      pu.u[3] = wB[2 * g + 1];
      short8 vf0 = *(const short8*)&Vs[cur][g * 2048 + ln * 32 + vsw];
      short8 vf1 = *(const short8*)&Vs[cur][g * 2048 + (16 + ln) * 32 + vsw];
      short8 vf2 = *(const short8*)&Vs[cur][g * 2048 + (32 + ln) * 32 + vsw];
      short8 vf3 = *(const short8*)&Vs[cur][g * 2048 + (48 + ln) * 32 + vsw];
      __builtin_amdgcn_s_setprio(1);
      o[0] = __builtin_amdgcn_mfma_f32_16x16x32_bf16(vf0, pu.s8, o[0], 0, 0, 0);
      o[1] = __builtin_amdgcn_mfma_f32_16x16x32_bf16(vf1, pu.s8, o[1], 0, 0, 0);
      o[2] = __builtin_amdgcn_mfma_f32_16x16x32_bf16(vf2, pu.s8, o[2], 0, 0, 0);
      o[3] = __builtin_amdgcn_mfma_f32_16x16x32_bf16(vf3, pu.s8, o[3], 0, 0, 0);
      __builtin_amdgcn_s_setprio(0);
    }
  };

  stage(seq(0), 0);
  int cur = 0;

  for (int c = 0; c < NCH; ++c) {
    __builtin_amdgcn_s_barrier();
    if (c + 1 < NCH) {
      stage(seq(c + 1), cur ^ 1);
      asm volatile("s_waitcnt vmcnt(8)" ::: "memory");   // stage(c) done; c+1 in flight
    } else {
      asm volatile("s_waitcnt vmcnt(0)" ::: "memory");
    }
    __builtin_amdgcn_sched_barrier(0);

    if (c < nA) {
      step(cur, (c == nA - 1) ? jdA : 8, qfA0, qfA1, lsA, oA);
    } else {
      int cl = c - nA;
      step(cur, (cl == nB - 1) ? jdB : 8, qfB0, qfB1, lsB, oB);
    }
    cur ^= 1;
  }

  // ---- final l reduction + store, both tiles ----
  int b = bh >> 4, h = bh & 15;
  lsA += __shfl_xor(lsA, 16);
  lsA += __shfl_xor(lsA, 32);
  lsB += __shfl_xor(lsB, 16);
  lsB += __shfl_xor(lsB, 32);
  float invA = 1.0f / lsA, invB = 1.0f / lsB;
  u16* rowA = AO + ((size_t)(b * L_ + q0A + ln) * H_ + h) * D_;
  u16* rowB = AO + ((size_t)(b * L_ + q0B + ln) * H_ + h) * D_;
#pragma unroll
  for (int dt = 0; dt < 4; ++dt) {
    union { u16 pk[4]; uint2 v; } uA, uB;
#pragma unroll
    for (int r = 0; r < 4; ++r) {
      uA.pk[r] = f2bf(oA[dt][r] * invA);
      uB.pk[r] = f2bf(oB[dt][r] * invB);
    }
    *(uint2*)(rowA + dt * 16 + kg * 4) = uA.v;
    *(uint2*)(rowB + dt * 16 + kg * 4) = uB.v;
  }
}

// ---------------- launch ----------------

extern "C" void kernel_launch(void* const* d_in, const int* in_sizes, int n_in,
                              void* d_out, int out_size, void* d_ws, size_t ws_size,
                              hipStream_t stream) {
  (void)in_sizes; (void)n_in; (void)out_size; (void)ws_size;
  const float* x   = (const float*)d_in[0];
  const int*   pos = (const int*)d_in[1];
  // d_in[2] = additive causal mask (we apply causal masking directly)
  const float* Wq  = (const float*)d_in[3];
  const float* Wk  = (const float*)d_in[4];
  const float* Wv  = (const float*)d_in[5];
  const float* Wo  = (const float*)d_in[6];

  char* ws = (char*)d_ws;
  u16* xbf = (u16*)ws;                        // 8 MB
  u16* Wt3 = (u16*)(ws + (size_t)( 8 << 20)); // 6 MB ([Wq|Wk|Wv]^T stacked)
  u16* Wto = (u16*)(ws + (size_t)(14 << 20)); // 2 MB
  u16* Qb  = (u16*)(ws + (size_t)(16 << 20)); // 8 MB each
  u16* Kb  = (u16*)(ws + (size_t)(24 << 20));
  u16* Vt  = (u16*)(ws + (size_t)(32 << 20)); // chunk-tiled, kv-permuted
  u16* AO  = (u16*)(ws + (size_t)(40 << 20));
  float2* tab = (float2*)(ws + (size_t)(48 << 20)); // 512 KB

  prep_k<<<6400, 256, 0, stream>>>(
      x, xbf, Wq, Wk, Wv, Wo,
      Wt3, Wt3 + (size_t)1048576, Wt3 + (size_t)2097152, Wto, pos, tab);
  qkv_gemm_k<<<512, 256, 0, stream>>>(xbf, Wt3, Qb, Kb, Vt, tab);
  attn_k<<<512, 256, 0, stream>>>(Qb, Kb, Vt, AO);
  oproj_k<<<512, 256, 0, stream>>>(AO, Wto, (float*)d_out);
}